// Round 9
// baseline (571.727 us; speedup 1.0000x reference)
//
#include <hip/hip_runtime.h>

#define NB 256   // batch
#define NT 512   // time steps
#define ND 128   // input dim
#define NU 128   // hidden dim
#define NC 64    // classes
#define SCL 2.8853900817779268f  // 2*log2(e): folds tanh 2x arg-scale + e^x -> 2^x

typedef _Float16 half2v __attribute__((ext_vector_type(2)));
typedef _Float16 half4v __attribute__((ext_vector_type(4)));
typedef _Float16 half8v __attribute__((ext_vector_type(8)));
typedef float f32x4 __attribute__((ext_vector_type(4)));

#define MFMA(a, b, c) __builtin_amdgcn_mfma_f32_16x16x32_f16((a), (b), (c), 0, 0, 0)

// packed f32x2 -> f16x2
__device__ __forceinline__ half2v pk2(float a, float b) {
  return __builtin_bit_cast(half2v, __builtin_amdgcn_cvt_pkrtz(a, b));
}

// tanh from pre-scaled s = 2x*log2e: tanh(x) = 1 - 2/(2^s + 1); exact limits.
__device__ __forceinline__ float tanh_s(float s) {
  float e = __builtin_amdgcn_exp2f(s);
  return fmaf(-2.0f, __builtin_amdgcn_rcpf(e + 1.0f), 1.0f);
}
// y' = th + tanh(s) - 1 = th - 2/(2^s+1): the "-1" shift lets the constant
// 1-vector be folded into the next GEMM's bias via column sums of W2/Wc.
__device__ __forceinline__ float ym1(float s, float th) {
  float e = __builtin_amdgcn_exp2f(s);
  return fmaf(-2.0f, __builtin_amdgcn_rcpf(e + 1.0f), th);
}

// LDS-only barrier (no vmem drain -> prefetches/stores stay in flight).
__device__ __forceinline__ void wg_barrier() {
  asm volatile("s_waitcnt lgkmcnt(0)\n\ts_barrier" ::: "memory");
}

// ===================== FUSED RNN: producers + recurrence + head =====================
// 16 blocks x 896 thr (14 waves), one dispatch for the whole model.
//   waves 0..7  : recurrence, hidden tile [16w,16w+16)  (r5 engine: 808 cyc/step)
//   waves 8..9  : classifier head (2 class tiles each), pipelined reads, f32 out
//   waves 10..13: th producers -- compute th_{t+4} = tanh(x@W1+b1) into an
//                 8-slot LDS ring, 4 steps ahead (2 ht tiles each, 8 MFMA/step)
// All off-chain work (head + producers) lives in the ~450-cyc shadow of the
// recurrence step (CU matrix pipe: 72 MFMA/step = ~350 cyc < 808). x-loads are
// issued 2 intervals (~1600 cyc) ahead. Eliminates k1 (28us) + TH workspace.
// y' = y-1 exchanged (1-vector folded into b2/bc via column sums).
// Ring safety: slot (t+4)&7 written at interval t; read at interval t+3
// (th_{t+4} loaded during interval t+3, used at t+4): 3 barriers separation.
__global__ __launch_bounds__(896, 1) void rnn_fused(
    const float* __restrict__ x, const float* __restrict__ W1,
    const float* __restrict__ b1v, const float* __restrict__ W2,
    const float* __restrict__ b2v, const float* __restrict__ Wc,
    const float* __restrict__ bcv, float* __restrict__ out)
{
  __shared__ _Float16 Ybuf[2][2048];  // y' image in frag order, double-buffered
  __shared__ _Float16 TR[8][2048];    // th ring: [slot][ht*256 + v*16 + q*4]

  const int tid = (int)threadIdx.x;
  const int w = tid >> 6;  // 0..7 rec, 8..9 head, 10..13 producer
  const int L = tid & 63;
  const int v = L & 15, q = L >> 4;
  const int b0 = (int)blockIdx.x * 16;
  const _Float16* rd = &Ybuf[0][0] + L * 8;  // y' frag read base (conflict-free)
  const f32x4 zero4 = (f32x4){0.f, 0.f, 0.f, 0.f};

  if (w < 8) {
    // ================= recurrence wave: hidden tile [16w,16w+16) =================
    half8v w2f[4];  // A-frags of W2^T, scaled SCL
#pragma unroll
    for (int kk = 0; kk < 4; ++kk) {
      half8v h;
#pragma unroll
      for (int j = 0; j < 8; ++j)
        h[j] = (_Float16)(SCL * W2[(size_t)(32 * kk + 8 * q + j) * NU + 16 * w + v]);
      w2f[kk] = h;
    }
    f32x4 racc, b2f;
    {
      const int h0 = 16 * w + 4 * q;
      float4 bb = *(const float4*)&b2v[h0];
      racc = (f32x4){SCL * bb.x, SCL * bb.y, SCL * bb.z, SCL * bb.w};
      // b2' = SCL*(b2 + sum_k W2[k,:])  (y-1 shift fold); racc stays SCL*b2.
      f32x4 cs = zero4;
#pragma unroll 4
      for (int k = 0; k < NU; ++k) {
        float4 ww = *(const float4*)&W2[(size_t)k * NU + h0];
        cs += (f32x4){ww.x, ww.y, ww.z, ww.w};
      }
      b2f = racc + (f32x4){SCL * cs[0], SCL * cs[1], SCL * cs[2], SCL * cs[3]};
    }
    // y' write slot in frag order (r5-verified mapping)
    _Float16* wr = &Ybuf[0][0] + (w >> 1) * 512 +
                   (v + 16 * (2 * (w & 1) + (q >> 1))) * 8 + 4 * (q & 1);
    // th ring read base for this wave/lane
    const _Float16* trr = &TR[0][0] + w * 256 + v * 16 + q * 4;

    __builtin_amdgcn_s_setprio(1);  // critical-chain waves win issue arbitration
    wg_barrier();                   // prologue sync: ring slots 0..3 ready

    half4v thr = *(const half4v*)trr;  // th_0 from slot 0

#define RSTEP(T_, BUF_)                                                       \
  {                                                                           \
    half2v ylo = pk2(ym1(racc[0], (float)thr[0]),                             \
                     ym1(racc[1], (float)thr[1]));                            \
    half2v yhi = pk2(ym1(racc[2], (float)thr[2]),                             \
                     ym1(racc[3], (float)thr[3]));                            \
    half4v y4 = {ylo[0], ylo[1], yhi[0], yhi[1]};                             \
    *(half4v*)(wr + (BUF_) * 2048) = y4;                                      \
    wg_barrier();                                                             \
    {                                                                         \
      half8v yf0 = *(const half8v*)(rd + (BUF_) * 2048 + 0);                  \
      half8v yf1 = *(const half8v*)(rd + (BUF_) * 2048 + 512);                \
      half8v yf2 = *(const half8v*)(rd + (BUF_) * 2048 + 1024);               \
      half8v yf3 = *(const half8v*)(rd + (BUF_) * 2048 + 1536);               \
      thr = *(const half4v*)(trr + (((T_) + 1) & 7) * 2048);                  \
      f32x4 ra = MFMA(w2f[0], yf0, b2f);  /* two independent 2-chains */      \
      f32x4 rb = MFMA(w2f[1], yf1, zero4);                                    \
      ra = MFMA(w2f[2], yf2, ra);                                             \
      rb = MFMA(w2f[3], yf3, rb);                                             \
      racc = ra + rb;                                                         \
    }                                                                         \
  }

#pragma unroll 1
    for (int t = 0; t < NT; t += 2) {
      RSTEP(t + 0, 0)
      RSTEP(t + 1, 1)
    }
#undef RSTEP

  } else if (w < 10) {
    // ================= head wave hw: class tiles {2hw, 2hw+1} =================
    const int hw = w - 8;
    half8v wcf[2][4];
    f32x4 bcf[2];
#pragma unroll
    for (int c2 = 0; c2 < 2; ++c2) {
      const int ct = 2 * hw + c2;
#pragma unroll
      for (int kk = 0; kk < 4; ++kk) {
        half8v h;
#pragma unroll
        for (int j = 0; j < 8; ++j)
          h[j] = (_Float16)Wc[(size_t)(32 * kk + 8 * q + j) * NC + 16 * ct + v];
        wcf[c2][kk] = h;
      }
      const int c0 = 16 * ct + 4 * q;
      float4 bb = *(const float4*)&bcv[c0];
      f32x4 cs = zero4;  // bc' = bc + sum_k Wc[k,:] (y-1 shift fold)
#pragma unroll 4
      for (int k = 0; k < NU; ++k) {
        float4 ww = *(const float4*)&Wc[(size_t)k * NC + c0];
        cs += (f32x4){ww.x, ww.y, ww.z, ww.w};
      }
      bcf[c2] = cs + (f32x4){bb.x, bb.y, bb.z, bb.w};
    }
    float* op = out + ((size_t)(b0 + v) * NT) * NC + 4 * q + 32 * hw;

    wg_barrier();  // prologue sync

    // Pipelined: reads for y_t issue after the MFMAs for y_{t-1} (LDS-quiet
    // window); frags carried in regs across the barrier (double-buffer-safe).
    half8v pf0, pf1, pf2, pf3;
#pragma unroll 1
    for (int t = 0; t < NT; ++t) {
      wg_barrier();  // barrier #t: y_t now visible in buf[t&1]
      if (t > 0) {
#pragma unroll
        for (int c2 = 0; c2 < 2; ++c2) {
          f32x4 oa = MFMA(wcf[c2][0], pf0, bcf[c2]);
          f32x4 ob = MFMA(wcf[c2][1], pf1, zero4);
          oa = MFMA(wcf[c2][2], pf2, oa);
          ob = MFMA(wcf[c2][3], pf3, ob);
          f32x4 oo = oa + ob;
          *(float4*)(op + (size_t)(t - 1) * NC + 16 * c2) =
              (float4){oo[0], oo[1], oo[2], oo[3]};
        }
      }
      const _Float16* rb = rd + (t & 1) * 2048;
      pf0 = *(const half8v*)(rb + 0);
      pf1 = *(const half8v*)(rb + 512);
      pf2 = *(const half8v*)(rb + 1024);
      pf3 = *(const half8v*)(rb + 1536);
    }
    asm volatile("s_waitcnt lgkmcnt(0)" ::: "memory");
#pragma unroll
    for (int c2 = 0; c2 < 2; ++c2) {
      f32x4 oa = MFMA(wcf[c2][0], pf0, bcf[c2]);
      f32x4 ob = MFMA(wcf[c2][1], pf1, zero4);
      oa = MFMA(wcf[c2][2], pf2, oa);
      ob = MFMA(wcf[c2][3], pf3, ob);
      f32x4 oo = oa + ob;
      *(float4*)(op + (size_t)(NT - 1) * NC + 16 * c2) =
          (float4){oo[0], oo[1], oo[2], oo[3]};
    }
    // NOTE: this path executes 1 (prologue) + NT (loop) barriers -- same as rec.

  } else {
    // ================= producer wave p: th tiles {2p, 2p+1} =================
    const int p = w - 10;
    half8v w1f[2][4];  // A-frags of W1^T for 2 tiles, scaled SCL
    f32x4 b1f[2];
#pragma unroll
    for (int tt = 0; tt < 2; ++tt) {
      const int ct = 2 * p + tt;
#pragma unroll
      for (int kk = 0; kk < 4; ++kk) {
        half8v h;
#pragma unroll
        for (int j = 0; j < 8; ++j)
          h[j] = (_Float16)(SCL * W1[(size_t)(32 * kk + 8 * q + j) * NU + 16 * ct + v]);
        w1f[tt][kk] = h;
      }
      float4 bb = *(const float4*)&b1v[16 * ct + 4 * q];
      b1f[tt] = (f32x4){SCL * bb.x, SCL * bb.y, SCL * bb.z, SCL * bb.w};
    }
    _Float16* trw = &TR[0][0] + v * 16 + q * 4;  // + slot*2048 + ht*256

#define LOADX(X_, S_)                                                         \
  {                                                                           \
    const float* xr_ = x + ((size_t)(b0 + v) * NT + (size_t)(S_)) * ND + 8 * q;\
    _Pragma("unroll")                                                         \
    for (int kk = 0; kk < 4; ++kk) {                                          \
      X_[2 * kk]     = *(const float4*)(xr_ + 32 * kk);                       \
      X_[2 * kk + 1] = *(const float4*)(xr_ + 32 * kk + 4);                   \
    }                                                                         \
  }

#define PRODUCE(S_, X_)                                                       \
  {                                                                           \
    half8v xf[4];                                                             \
    _Pragma("unroll")                                                         \
    for (int kk = 0; kk < 4; ++kk) {                                          \
      float4 a = X_[2 * kk], b = X_[2 * kk + 1];                              \
      half2v p0 = pk2(a.x, a.y), p1 = pk2(a.z, a.w);                          \
      half2v p2 = pk2(b.x, b.y), p3 = pk2(b.z, b.w);                          \
      xf[kk] = (half8v){p0[0], p0[1], p1[0], p1[1], p2[0], p2[1], p3[0], p3[1]};\
    }                                                                         \
    _Pragma("unroll")                                                         \
    for (int tt = 0; tt < 2; ++tt) {                                          \
      f32x4 acc = b1f[tt];                                                    \
      _Pragma("unroll")                                                       \
      for (int kk = 0; kk < 4; ++kk) acc = MFMA(w1f[tt][kk], xf[kk], acc);    \
      half2v lo = pk2(tanh_s(acc[0]), tanh_s(acc[1]));                        \
      half2v hi = pk2(tanh_s(acc[2]), tanh_s(acc[3]));                        \
      half4v z4 = {lo[0], lo[1], hi[0], hi[1]};                               \
      *(half4v*)(trw + ((S_) & 7) * 2048 + (2 * p + tt) * 256) = z4;          \
    }                                                                         \
  }

    float4 X0[8], X1[8];
    // prologue: fill ring slots 0..3; leave X0=x(4), X1=x(5) in flight
    LOADX(X0, 0) LOADX(X1, 1)
    PRODUCE(0, X0) LOADX(X0, 2)
    PRODUCE(1, X1) LOADX(X1, 3)
    PRODUCE(2, X0) LOADX(X0, 4)
    PRODUCE(3, X1) LOADX(X1, 5)

    wg_barrier();  // prologue sync (drains our ds_writes; vmem stays in flight)

#pragma unroll 1
    for (int t = 0; t < NT; t += 2) {
      if (t + 4 < NT) { PRODUCE(t + 4, X0) }
      if (t + 6 < NT) { LOADX(X0, t + 6) }
      wg_barrier();
      if (t + 5 < NT) { PRODUCE(t + 5, X1) }
      if (t + 7 < NT) { LOADX(X1, t + 7) }
      wg_barrier();
    }
#undef PRODUCE
#undef LOADX
  }
}

extern "C" void kernel_launch(void* const* d_in, const int* in_sizes, int n_in,
                              void* d_out, int out_size, void* d_ws, size_t ws_size,
                              hipStream_t stream) {
  (void)in_sizes; (void)n_in; (void)out_size; (void)d_ws; (void)ws_size;
  const float* x   = (const float*)d_in[0];
  const float* W1  = (const float*)d_in[1];
  const float* b1v = (const float*)d_in[2];
  const float* W2  = (const float*)d_in[3];
  const float* b2v = (const float*)d_in[4];
  const float* Wc  = (const float*)d_in[5];
  const float* bcv = (const float*)d_in[6];
  float* out = (float*)d_out;

  hipLaunchKernelGGL(rnn_fused, dim3(NB / 16), dim3(896), 0, stream,
                     x, W1, b1v, W2, b2v, Wc, bcv, out);
}

// Round 10
// 293.332 us; speedup vs baseline: 1.9491x; 1.9491x over previous
//
#include <hip/hip_runtime.h>

#define NB 256   // batch
#define NT 512   // time steps
#define ND 128   // input dim
#define NU 128   // hidden dim
#define NC 64    // classes
#define NM (NB * NT)   // 131072 flat rows
#define YP 136         // LDS row pitch in halfs for k1 weight tile
#define SCL 2.8853900817779268f  // 2*log2(e): folds tanh 2x arg-scale + e^x -> 2^x

typedef _Float16 half2v __attribute__((ext_vector_type(2)));
typedef _Float16 half4v __attribute__((ext_vector_type(4)));
typedef _Float16 half8v __attribute__((ext_vector_type(8)));
typedef float f32x4 __attribute__((ext_vector_type(4)));
typedef float v2f __attribute__((ext_vector_type(2)));

#define MFMA(a, b, c) __builtin_amdgcn_mfma_f32_16x16x32_f16((a), (b), (c), 0, 0, 0)

// packed f32x2 -> f16x2
__device__ __forceinline__ half2v pk2(float a, float b) {
  return __builtin_bit_cast(half2v, __builtin_amdgcn_cvt_pkrtz(a, b));
}

// tanh from pre-scaled s = 2x*log2e: tanh(x) = 1 - 2/(2^s + 1); exact limits.
__device__ __forceinline__ float tanh_s(float s) {
  float e = __builtin_amdgcn_exp2f(s);
  return fmaf(-2.0f, __builtin_amdgcn_rcpf(e + 1.0f), 1.0f);
}
// y' = th + tanh(s) - 1 = th - 2/(2^s+1): the "-1" shift lets the constant
// 1-vector be folded into the next GEMM's bias via column sums of W2/Wc.
__device__ __forceinline__ float ym1(float s, float th) {
  float e = __builtin_amdgcn_exp2f(s);
  return fmaf(-2.0f, __builtin_amdgcn_rcpf(e + 1.0f), th);
}

// LDS-only barrier (no vmem drain -> prefetches/stores stay in flight).
__device__ __forceinline__ void wg_barrier() {
  asm volatile("s_waitcnt lgkmcnt(0)\n\ts_barrier" ::: "memory");
}

// ===================== K1: TH = tanh(x @ W1 + b1) -> f16 =====================
// 1024 blocks x 512 thr, 128 rows/block (was 2048x256x64): halves the W1
// L2 re-fetch (64KB/block) and the stage+sync prologue count; stage runs on
// 512 threads. 34KB LDS -> exactly 4 blocks/CU.
__global__ __launch_bounds__(512, 1) void k1_inproj(
    const float* __restrict__ x, const float* __restrict__ W1,
    const float* __restrict__ b1v, _Float16* __restrict__ TH)
{
  __shared__ _Float16 W1T[ND * YP];  // W1^T[n][k], pre-scaled by SCL
  const int tid = (int)threadIdx.x;
  for (int i = tid; i < ND * NU / 2; i += 512) {
    int n = i & 127, kh = i >> 7;
    half2v p = {(_Float16)(SCL * W1[(size_t)(2 * kh) * NU + n]),
                (_Float16)(SCL * W1[(size_t)(2 * kh + 1) * NU + n])};
    *(half2v*)&W1T[n * YP + 2 * kh] = p;
  }
  __syncthreads();

  const int L = tid & 63, wv = tid >> 6;
  const int v = L & 15, q = L >> 4;
  const int m0 = (int)blockIdx.x * 128 + wv * 16;

  const float* xr = x + (size_t)(m0 + v) * ND + 8 * q;
  half8v xf[4];
#pragma unroll
  for (int kk = 0; kk < 4; ++kk) {
    float4 a = *(const float4*)(xr + 32 * kk);
    float4 b = *(const float4*)(xr + 32 * kk + 4);
    half2v p0 = pk2(a.x, a.y), p1 = pk2(a.z, a.w);
    half2v p2 = pk2(b.x, b.y), p3 = pk2(b.z, b.w);
    xf[kk] = (half8v){p0[0], p0[1], p1[0], p1[1], p2[0], p2[1], p3[0], p3[1]};
  }

#pragma unroll
  for (int ht = 0; ht < 8; ++ht) {
    f32x4 acc;
    {
      float4 bb = *(const float4*)&b1v[16 * ht + 4 * q];
      acc = (f32x4){SCL * bb.x, SCL * bb.y, SCL * bb.z, SCL * bb.w};
    }
#pragma unroll
    for (int kk = 0; kk < 4; ++kk) {
      half8v wa = *(const half8v*)&W1T[(16 * ht + v) * YP + 32 * kk + 8 * q];
      acc = MFMA(wa, xf[kk], acc);
    }
    half2v zlo = pk2(tanh_s(acc[0]), tanh_s(acc[1]));
    half2v zhi = pk2(tanh_s(acc[2]), tanh_s(acc[3]));
    half4v z = {zlo[0], zlo[1], zhi[0], zhi[1]};
    *(half4v*)&TH[(size_t)(m0 + v) * NU + 16 * ht + 4 * q] = z;
  }
}

// ===================== K2: recurrence (8 waves) + head (2 waves) =====================
// [r5 engine, byte-identical: measured 172.5 us, best of 10 rounds.]
// 16 blocks x 640 thr. y'-image stored in B-FRAGMENT ORDER: YF[kk][lane][j]
// (frag kk at halfs kk*512, lane chunk = 16B). Read: lane L -> b128 at
// kk*1024B + L*16B -- consecutive lanes, consecutive banks, ZERO read
// conflicts. Write: lane (v,q) of wave w -> one b64 at frag w>>1,
// lane' v+16*(2(w&1)+(q>>1)), half-offset 4*(q&1) (4-way, negligible).
// Head waves read frags for y_t AFTER issuing MFMAs for y_{t-1} (off the
// post-barrier burst); rec waves run at s_setprio(1).
__global__ __launch_bounds__(640, 1) void k2_recur(
    const _Float16* __restrict__ TH, const float* __restrict__ W2,
    const float* __restrict__ b2v, const float* __restrict__ Wc,
    const float* __restrict__ bcv, float* __restrict__ out)
{
  __shared__ _Float16 Ybuf[2][2048];  // y' image in frag order, double-buffered

  const int tid = (int)threadIdx.x;
  const int w = tid >> 6;  // 0..7 recurrence, 8..9 head
  const int L = tid & 63;
  const int v = L & 15, q = L >> 4;
  const int b0 = (int)blockIdx.x * 16;
  const _Float16* rd = &Ybuf[0][0] + L * 8;  // lane chunk; frag kk at +kk*512
  const f32x4 zero4 = (f32x4){0.f, 0.f, 0.f, 0.f};

  if (w < 8) {
    // ---------------- recurrence wave: hidden tile [16w,16w+16) ----------------
    half8v w2f[4];  // A-frags of W2^T, scaled SCL
#pragma unroll
    for (int kk = 0; kk < 4; ++kk) {
      half8v h;
#pragma unroll
      for (int j = 0; j < 8; ++j)
        h[j] = (_Float16)(SCL * W2[(size_t)(32 * kk + 8 * q + j) * NU + 16 * w + v]);
      w2f[kk] = h;
    }
    f32x4 racc, b2f;
    {
      const int h0 = 16 * w + 4 * q;
      float4 bb = *(const float4*)&b2v[h0];
      racc = (f32x4){SCL * bb.x, SCL * bb.y, SCL * bb.z, SCL * bb.w};
      // b2' = SCL*(b2 + sum_k W2[k,:])  (y-1 shift fold); racc stays SCL*b2.
      f32x4 cs = zero4;
#pragma unroll 4
      for (int k = 0; k < NU; ++k) {
        float4 ww = *(const float4*)&W2[(size_t)k * NU + h0];
        cs += (f32x4){ww.x, ww.y, ww.z, ww.w};
      }
      b2f = racc + (f32x4){SCL * cs[0], SCL * cs[1], SCL * cs[2], SCL * cs[3]};
    }

    const _Float16* thp = TH + ((size_t)(b0 + v) * NT) * NU + 16 * w + 4 * q;
    // write slot in frag order: frag w>>1, lane' = v + 16*(2*(w&1)+(q>>1)),
    // half offset 4*(q&1)
    _Float16* wr = &Ybuf[0][0] + (w >> 1) * 512 +
                   (v + 16 * (2 * (w & 1) + (q >> 1))) * 8 + 4 * (q & 1);

    // th prefetch ring (4 deep), one 8B load per step
    half4v thr0 = *(const half4v*)(thp + 0 * NU);
    half4v thr1 = *(const half4v*)(thp + 1 * NU);
    half4v thr2 = *(const half4v*)(thp + 2 * NU);
    half4v thr3 = *(const half4v*)(thp + 3 * NU);

    __builtin_amdgcn_s_setprio(1);  // critical-chain waves win LDS arbitration

#define RSTEP(T_, THR_, BUF_)                                                 \
  {                                                                           \
    half2v ylo = pk2(ym1(racc[0], (float)THR_[0]),                            \
                     ym1(racc[1], (float)THR_[1]));                           \
    half2v yhi = pk2(ym1(racc[2], (float)THR_[2]),                            \
                     ym1(racc[3], (float)THR_[3]));                           \
    half4v y4 = {ylo[0], ylo[1], yhi[0], yhi[1]};                             \
    *(half4v*)(wr + (BUF_) * 2048) = y4;                                      \
    {                                                                         \
      int tn = (T_) + 4; tn = tn < NT ? tn : NT - 1;                          \
      THR_ = *(const half4v*)(thp + (size_t)tn * NU);                         \
    }                                                                         \
    wg_barrier();                                                             \
    {                                                                         \
      half8v yf0 = *(const half8v*)(rd + (BUF_) * 2048 + 0);                  \
      half8v yf1 = *(const half8v*)(rd + (BUF_) * 2048 + 512);                \
      half8v yf2 = *(const half8v*)(rd + (BUF_) * 2048 + 1024);               \
      half8v yf3 = *(const half8v*)(rd + (BUF_) * 2048 + 1536);               \
      f32x4 ra = MFMA(w2f[0], yf0, b2f);  /* two independent 2-chains */      \
      f32x4 rb = MFMA(w2f[1], yf1, zero4);                                    \
      ra = MFMA(w2f[2], yf2, ra);                                             \
      rb = MFMA(w2f[3], yf3, rb);                                             \
      racc = ra + rb;                                                         \
    }                                                                         \
  }

#pragma unroll 1
    for (int t = 0; t < NT; t += 4) {
      RSTEP(t + 0, thr0, 0)
      RSTEP(t + 1, thr1, 1)
      RSTEP(t + 2, thr2, 0)
      RSTEP(t + 3, thr3, 1)
    }
#undef RSTEP
  } else {
    // ---------------- head wave hw = w-8: class tiles {2hw, 2hw+1} ----------------
    const int hw = w - 8;
    half8v wcf[2][4];
    f32x4 bcf[2];
#pragma unroll
    for (int c2 = 0; c2 < 2; ++c2) {
      const int ct = 2 * hw + c2;
#pragma unroll
      for (int kk = 0; kk < 4; ++kk) {
        half8v h;
#pragma unroll
        for (int j = 0; j < 8; ++j)
          h[j] = (_Float16)Wc[(size_t)(32 * kk + 8 * q + j) * NC + 16 * ct + v];
        wcf[c2][kk] = h;
      }
      const int c0 = 16 * ct + 4 * q;
      float4 bb = *(const float4*)&bcv[c0];
      f32x4 cs = zero4;  // bc' = bc + sum_k Wc[k,:] (y-1 shift fold)
#pragma unroll 4
      for (int k = 0; k < NU; ++k) {
        float4 ww = *(const float4*)&Wc[(size_t)k * NC + c0];
        cs += (f32x4){ww.x, ww.y, ww.z, ww.w};
      }
      bcf[c2] = cs + (f32x4){bb.x, bb.y, bb.z, bb.w};
    }
    float* op = out + ((size_t)(b0 + v) * NT) * NC + 4 * q + 32 * hw;

    // Pipelined: reads for y_t issue after the MFMAs for y_{t-1}, landing in
    // the LDS-quiet window. Frags carried in regs across the barrier.
    // Double-buffer-safe: reads drain at our lgkmcnt(0) before barrier t+1;
    // buf[t&1] is only rewritten (y_{t+2}) after that.
    half8v pf0, pf1, pf2, pf3;
#pragma unroll 1
    for (int t = 0; t < NT; ++t) {
      wg_barrier();  // barrier #t: y_t now visible in buf[t&1]
      if (t > 0) {
#pragma unroll
        for (int c2 = 0; c2 < 2; ++c2) {
          f32x4 oa = MFMA(wcf[c2][0], pf0, bcf[c2]);
          f32x4 ob = MFMA(wcf[c2][1], pf1, zero4);
          oa = MFMA(wcf[c2][2], pf2, oa);
          ob = MFMA(wcf[c2][3], pf3, ob);
          f32x4 oo = oa + ob;
          *(float4*)(op + (size_t)(t - 1) * NC + 16 * c2) =
              (float4){oo[0], oo[1], oo[2], oo[3]};
        }
      }
      const _Float16* rb = rd + (t & 1) * 2048;
      pf0 = *(const half8v*)(rb + 0);
      pf1 = *(const half8v*)(rb + 512);
      pf2 = *(const half8v*)(rb + 1024);
      pf3 = *(const half8v*)(rb + 1536);
    }
    asm volatile("s_waitcnt lgkmcnt(0)" ::: "memory");
#pragma unroll
    for (int c2 = 0; c2 < 2; ++c2) {
      f32x4 oa = MFMA(wcf[c2][0], pf0, bcf[c2]);
      f32x4 ob = MFMA(wcf[c2][1], pf1, zero4);
      oa = MFMA(wcf[c2][2], pf2, oa);
      ob = MFMA(wcf[c2][3], pf3, ob);
      f32x4 oo = oa + ob;
      *(float4*)(op + (size_t)(NT - 1) * NC + 16 * c2) =
          (float4){oo[0], oo[1], oo[2], oo[3]};
    }
  }
}

// ===================== fallback (round-2 kernel, no workspace) =====================
__device__ __forceinline__ float fast_tanh(float x) {
  float e = __expf(2.0f * x);
  return 1.0f - 2.0f / (e + 1.0f);
}
__device__ __forceinline__ float bcast(float val, int i) {
  return __builtin_bit_cast(float, __builtin_amdgcn_readlane(__builtin_bit_cast(int, val), i));
}

__global__ __launch_bounds__(256, 1) void rnn_fallback(
    const float* __restrict__ x, const float* __restrict__ W1,
    const float* __restrict__ b1v, const float* __restrict__ W2,
    const float* __restrict__ b2v, const float* __restrict__ Wc,
    const float* __restrict__ bcv, float* __restrict__ out)
{
  __shared__ float xring[16][ND];
  __shared__ float pH[2][4][NU];
  __shared__ float pR[2][4][NU];
  __shared__ float pC[2][4][NC];

  const int tid  = (int)threadIdx.x;
  const int lane = tid & 63;
  const int kg   = tid >> 6;
  const int b    = (int)blockIdx.x;
  const float4* xr4 = (const float4*)(x + (size_t)b * NT * ND);

  v2f w1f[32], w2f[32];
  float wcf[32];
#pragma unroll
  for (int i = 0; i < 32; ++i) {
    int k = kg * 32 + i;
    w1f[i] = (v2f){W1[k * NU + lane], W1[k * NU + lane + 64]};
    w2f[i] = (v2f){W2[k * NU + lane], W2[k * NU + lane + 64]};
    wcf[i] = Wc[k * NC + lane];
  }
  const float biasc = bcv[lane];
  float bias1 = 0.f, bias2 = 0.f;
  if (lane < 32) { bias1 = b1v[kg * 32 + lane]; bias2 = b2v[kg * 32 + lane]; }

  float4 stg = make_float4(0.f, 0.f, 0.f, 0.f);
  if (lane < 32) {
    float4 a0 = xr4[(kg + 0) * 32 + lane];
    float4 a1 = xr4[(kg + 4) * 32 + lane];
    ((float4*)xring[kg + 0])[lane] = a0;
    ((float4*)xring[kg + 4])[lane] = a1;
    stg = xr4[(kg + 8) * 32 + lane];
  }
  float yseg = 0.f;
  wg_barrier();

  for (int t = 0; t < NT; ++t) {
    const int pb = t & 1;
    v2f accH0 = {0.f, 0.f}, accH1 = {0.f, 0.f};
    const float4* xb = (const float4*)&xring[t & 15][kg * 32];
#pragma unroll
    for (int i = 0; i < 4; ++i) {
      float4 xa = xb[2 * i];
      float4 xc = xb[2 * i + 1];
      accH0 = w1f[8*i+0] * (v2f){xa.x, xa.x} + accH0;
      accH1 = w1f[8*i+1] * (v2f){xa.y, xa.y} + accH1;
      accH0 = w1f[8*i+2] * (v2f){xa.z, xa.z} + accH0;
      accH1 = w1f[8*i+3] * (v2f){xa.w, xa.w} + accH1;
      accH0 = w1f[8*i+4] * (v2f){xc.x, xc.x} + accH0;
      accH1 = w1f[8*i+5] * (v2f){xc.y, xc.y} + accH1;
      accH0 = w1f[8*i+6] * (v2f){xc.z, xc.z} + accH0;
      accH1 = w1f[8*i+7] * (v2f){xc.w, xc.w} + accH1;
    }
    v2f accH = accH0 + accH1;
    v2f accR0 = {0.f, 0.f}, accR1 = {0.f, 0.f};
    float accC0 = 0.f, accC1 = 0.f;
#pragma unroll
    for (int i = 0; i < 16; ++i) {
      float s0 = bcast(yseg, 2 * i);
      float s1 = bcast(yseg, 2 * i + 1);
      accR0 = w2f[2*i+0] * (v2f){s0, s0} + accR0;
      accR1 = w2f[2*i+1] * (v2f){s1, s1} + accR1;
      accC0 = fmaf(s0, wcf[2*i+0], accC0);
      accC1 = fmaf(s1, wcf[2*i+1], accC1);
    }
    v2f accR = accR0 + accR1;
    float accC = accC0 + accC1;

    pH[pb][kg][lane]      = accH.x;
    pH[pb][kg][lane + 64] = accH.y;
    pR[pb][kg][lane]      = accR.x;
    pR[pb][kg][lane + 64] = accR.y;
    pC[pb][kg][lane]      = accC;

    if (kg == (t & 3)) {
      if (lane < 32) {
        ((float4*)xring[(t + 8) & 15])[lane] = stg;
        int r = t + 12; r = (r < NT) ? r : (NT - 1);
        stg = xr4[r * 32 + lane];
      }
    }
    wg_barrier();
    if (lane < 32) {
      const int j = kg * 32 + lane;
      float hs = bias1, rs = bias2;
#pragma unroll
      for (int g = 0; g < 4; ++g) { hs += pH[pb][g][j]; rs += pR[pb][g][j]; }
      yseg = fast_tanh(hs) + fast_tanh(rs);
    }
    if (kg == ((t + 2) & 3) && t >= 1) {
      float cs = biasc;
#pragma unroll
      for (int g = 0; g < 4; ++g) cs += pC[pb][g][lane];
      out[((size_t)b * NT + (t - 1)) * NC + lane] = cs;
    }
  }
  float accC0 = 0.f, accC1 = 0.f;
#pragma unroll
  for (int i = 0; i < 16; ++i) {
    float s0 = bcast(yseg, 2 * i);
    float s1 = bcast(yseg, 2 * i + 1);
    accC0 = fmaf(s0, wcf[2*i+0], accC0);
    accC1 = fmaf(s1, wcf[2*i+1], accC1);
  }
  pC[0][kg][lane] = accC0 + accC1;
  wg_barrier();
  if (kg == 0) {
    float cs = biasc;
#pragma unroll
    for (int g = 0; g < 4; ++g) cs += pC[0][g][lane];
    out[((size_t)b * NT + (NT - 1)) * NC + lane] = cs;
  }
}

extern "C" void kernel_launch(void* const* d_in, const int* in_sizes, int n_in,
                              void* d_out, int out_size, void* d_ws, size_t ws_size,
                              hipStream_t stream) {
  (void)in_sizes; (void)n_in; (void)out_size;
  const float* x   = (const float*)d_in[0];
  const float* W1  = (const float*)d_in[1];
  const float* b1v = (const float*)d_in[2];
  const float* W2  = (const float*)d_in[3];
  const float* b2v = (const float*)d_in[4];
  const float* Wc  = (const float*)d_in[5];
  const float* bcv = (const float*)d_in[6];
  float* out = (float*)d_out;

  const size_t need = (size_t)NM * NU * 2;  // TH f16 = 32 MiB (no Y workspace)
  if (ws_size >= need) {
    _Float16* TH = (_Float16*)d_ws;
    hipLaunchKernelGGL(k1_inproj, dim3(NM / 128), dim3(512), 0, stream, x, W1, b1v, TH);
    hipLaunchKernelGGL(k2_recur, dim3(NB / 16), dim3(640), 0, stream,
                       TH, W2, b2v, Wc, bcv, out);
  } else {
    hipLaunchKernelGGL(rnn_fallback, dim3(NB), dim3(256), 0, stream,
                       x, W1, b1v, W2, b2v, Wc, bcv, out);
  }
}